// Round 5
// baseline (639.765 us; speedup 1.0000x reference)
//
#include <hip/hip_runtime.h>
#include <stdint.h>

#define Bb 64
#define Hh 128
#define Ww 128
#define Cc 21
#define Pp 49152          // NUM_SAMPLED
#define Kk 36864          // NUM_UNCERTAIN
#define NR 12288          // NUM_RANDOM

#define BINS 2048         // 11-bit digits; pass shifts 16/27/38 (bits >=47 are 0)
#define TILE 4096         // elements per sort tile
#define TILES 12          // Pp / TILE
#define NBLK (Bb * TILES) // 768 sample/scatter blocks
#define HWORDS ((size_t)Bb * BINS * TILES)   // u32 words per hist table (1.57M = 6.29 MB)

typedef uint32_t u32;
typedef uint64_t u64;
typedef unsigned short u16;

// XCD-affine decode: all TILES blocks of segment s have blk%8 == s%8, so the
// round-robin block->XCD dispatch keeps a segment's r/w window in ONE XCD's
// L2. Performance heuristic only; correctness never depends on placement.
#define DECODE_ST const int s = blk & 63; const int t = blk >> 6;

// 11-bit ballot digit-match: mask of lanes in this wave holding digit d.
__device__ __forceinline__ u64 match11(u32 d) {
    u64 m = ~0ull;
    #pragma unroll
    for (int bit = 0; bit < 11; ++bit) {
        u64 bl = __ballot((d >> bit) & 1u);
        m &= ((d >> bit) & 1u) ? bl : ~bl;
    }
    return m;
}

// ---------------------------------------------------------------------------
// Kernel 0: compact channel-0 plane: planes[b][h][w] = logits[b][h][w][0].
// ---------------------------------------------------------------------------
__global__ __launch_bounds__(256) void extract_kernel(const float* __restrict__ logits,
                                                      float* __restrict__ planes) {
    int gid = blockIdx.x * blockDim.x + threadIdx.x;   // [0, B*H*W)
    planes[gid] = logits[(size_t)gid * Cc];
}

// ---------------------------------------------------------------------------
// Kernel 1: bilinear sample (64 KB plane staged in LDS), build sortable key,
// fused pass-0 per-tile histogram. key = fp32 bits of |interp| (order-
// isomorphic for non-negative floats); element = (key << 16) | idx.
// fp contract OFF: the sort permutation feeds the output directly — bit-exact
// numpy arithmetic required (one rank flip = O(1) absmax error).
// ---------------------------------------------------------------------------
__global__ __launch_bounds__(256) void sample_key_kernel(const float* __restrict__ planes,
                                                         const float2* __restrict__ coords,
                                                         u64* __restrict__ keys,
                                                         u32* __restrict__ hist) {
#pragma clang fp contract(off)
    __shared__ float pl[Hh * Ww];      // 64 KB
    __shared__ u32 h[BINS];            // 8 KB
    const int tid = threadIdx.x;
    const int blk = blockIdx.x;
    DECODE_ST

    for (int i = tid; i < BINS; i += 256) h[i] = 0;
    const float4* p4 = (const float4*)(planes + s * (Hh * Ww));
    float4* l4 = (float4*)pl;
    #pragma unroll
    for (int i = 0; i < 16; ++i) l4[i * 256 + tid] = p4[i * 256 + tid];
    __syncthreads();

    #pragma unroll 4
    for (int i = 0; i < 16; ++i) {
        int idx = t * TILE + i * 256 + tid;            // point index within segment
        int gid = s * Pp + idx;
        float2 c = coords[gid];
        float xf = c.x * 127.0f;                       // coords[...,0] -> H axis
        float yf = c.y * 127.0f;                       // coords[...,1] -> W axis
        float x0 = floorf(xf), x1 = ceilf(xf);
        float y0 = floorf(yf), y1 = ceilf(yf);
        float mux = xf - x0;
        float muy = yf - y0;
        int x0i = (int)x0, x1i = (int)x1, y0i = (int)y0, y1i = (int)y1;
        float p1 = pl[x0i * Ww + y0i];
        float p2 = pl[x1i * Ww + y0i];
        float p3 = pl[x0i * Ww + y1i];
        float p4v = pl[x1i * Ww + y1i];
        float p12 = p1 * (1.0f - mux) + p2 * mux;
        float p34 = p3 * (1.0f - mux) + p4v * mux;
        float r   = p12 * (1.0f - muy) + p34 * muy;
        u32 kb = __float_as_uint(r) & 0x7fffffffu;     // |r| bits
        keys[gid] = ((u64)kb << 16) | (u32)idx;
        atomicAdd(&h[kb & (BINS - 1)], 1u);            // pass-0 digit (uniform)
    }
    __syncthreads();
    for (int j = 0; j < 8; ++j) {
        int d = tid * 8 + j;
        hist[((size_t)s * BINS + d) * TILES + t] = h[d];
    }
}

// ---------------------------------------------------------------------------
// Kernel 2: per-segment exclusive scan: dst[s][d][t] = prefix of src counts
// in (digit, tile) order. src may equal dst (in-place).
// ---------------------------------------------------------------------------
__global__ __launch_bounds__(1024) void scan_kernel(const u32* __restrict__ src,
                                                    u32* __restrict__ dst) {
    __shared__ u32 wsum[16];
    const int s = blockIdx.x;
    const int tid = threadIdx.x;
    const int lane = tid & 63;
    const int w = tid >> 6;
    const u32* sb = src + (size_t)s * BINS * TILES;
    u32* db = dst + (size_t)s * BINS * TILES;
    const int d0 = tid * 2, d1 = tid * 2 + 1;

    u32 c0[TILES], c1[TILES];
    u32 t0 = 0, t1 = 0;
    #pragma unroll
    for (int t = 0; t < TILES; ++t) { c0[t] = sb[d0 * TILES + t]; t0 += c0[t]; }
    #pragma unroll
    for (int t = 0; t < TILES; ++t) { c1[t] = sb[d1 * TILES + t]; t1 += c1[t]; }
    u32 ts = t0 + t1;

    u32 sc = ts;
    for (int o = 1; o < 64; o <<= 1) {
        u32 n = __shfl_up(sc, o);
        if (lane >= o) sc += n;
    }
    if (lane == 63) wsum[w] = sc;
    __syncthreads();
    if (tid == 0) {
        u32 run = 0;
        for (int i = 0; i < 16; ++i) { u32 v = wsum[i]; wsum[i] = run; run += v; }
    }
    __syncthreads();
    u32 excl = sc - ts + wsum[w];

    u32 r = excl;
    #pragma unroll
    for (int t = 0; t < TILES; ++t) { u32 v = c0[t]; db[d0 * TILES + t] = r; r += v; }
    r = excl + t0;
    #pragma unroll
    for (int t = 0; t < TILES; ++t) { u32 v = c1[t]; db[d1 * TILES + t] = r; r += v; }
}

// ---------------------------------------------------------------------------
// Kernel 3: stable scatter with LDS local reorder + linear run-contiguous
// global write. match11 computed ONCE per element (cached digit/rank/count/
// leader reused in phase B). Phase C additionally builds the NEXT pass's
// per-(digit, dest-tile) histogram via XCD-local global atomics — this
// replaces the standalone hist kernels entirely (counts are order-invariant,
// so atomic timing doesn't affect stability).
// Final pass: emit out[s][g] = coords[s][idx] directly for g < K.
// ---------------------------------------------------------------------------
__global__ __launch_bounds__(256) void scatter_kernel(const u64* __restrict__ in,
                                                      u64* __restrict__ out_keys,
                                                      const u32* __restrict__ off,
                                                      u32* __restrict__ hist_next,
                                                      int shift, int shift_next,
                                                      int final_pass,
                                                      const float2* __restrict__ coords,
                                                      float2* __restrict__ out) {
    __shared__ u64 el[TILE];           // 32 KB
    __shared__ u16 wh[BINS * 4];       // 16 KB  [digit][wave] counts -> local bases
    __shared__ u16 dl[BINS];           // 4 KB   delta[d] (mod 2^16)
    __shared__ u32 aux[4];
    const int tid = threadIdx.x;
    const int lane = tid & 63;
    const int w = tid >> 6;
    const int blk = blockIdx.x;
    DECODE_ST
    const u64* src = in + (size_t)s * Pp + t * TILE;

    for (int i = tid; i < BINS * 4; i += 256) wh[i] = 0;
    u64 v[16];
    #pragma unroll
    for (int i = 0; i < 16; ++i) v[i] = src[w * 1024 + i * 64 + lane];
    __syncthreads();

    // phase A: per-wave digit histogram; cache match results for phase B.
    // pk[i] = before | (cnt << 8) | (leader << 16)
    const u64 ltmask = (1ull << lane) - 1ull;
    u32 dg[16], pk[16];
    volatile u16* vwh = wh;
    #pragma unroll 2
    for (int i = 0; i < 16; ++i) {
        u32 d = (u32)(v[i] >> shift) & (BINS - 1);
        u64 m = match11(d);
        u32 before = (u32)__popcll(m & ltmask);
        u32 cnt = (u32)__popcll(m);
        bool lead = (lane == __ffsll((unsigned long long)m) - 1);
        dg[i] = d;
        pk[i] = before | (cnt << 8) | (lead ? 0x10000u : 0u);
        if (lead) {
            u32 p = d * 4 + w;
            vwh[p] = (u16)(vwh[p] + cnt);
        }
    }
    __syncthreads();

    // scan: thread owns 8 digits; local exclusive digit bases + per-wave bases.
    const int d0 = tid * 8;
    u32 dtot[8];
    u32 t8 = 0;
    #pragma unroll
    for (int j = 0; j < 8; ++j) {
        int d = d0 + j;
        u32 c = (u32)wh[d * 4 + 0] + wh[d * 4 + 1] + wh[d * 4 + 2] + wh[d * 4 + 3];
        dtot[j] = c;
        t8 += c;
    }
    u32 sc = t8;
    for (int o = 1; o < 64; o <<= 1) {
        u32 n = __shfl_up(sc, o);
        if (lane >= o) sc += n;
    }
    if (lane == 63) aux[w] = sc;
    __syncthreads();
    if (tid == 0) {
        u32 run = 0;
        for (int i = 0; i < 4; ++i) { u32 x = aux[i]; aux[i] = run; run += x; }
    }
    __syncthreads();
    u32 run = sc - t8 + aux[w];       // exclusive base for this thread's digits
    #pragma unroll
    for (int j = 0; j < 8; ++j) {
        int d = d0 + j;
        u32 ls = run;                 // local_start[d]
        u32 g = off[((size_t)s * BINS + d) * TILES + t];
        dl[d] = (u16)(g - ls);
        u32 c0 = wh[d * 4 + 0], c1 = wh[d * 4 + 1], c2 = wh[d * 4 + 2];
        wh[d * 4 + 0] = (u16)ls;
        wh[d * 4 + 1] = (u16)(ls + c0);
        wh[d * 4 + 2] = (u16)(ls + c0 + c1);
        wh[d * 4 + 3] = (u16)(ls + c0 + c1 + c2);
        run += dtot[j];
    }
    __syncthreads();

    // phase B: stable scatter into LDS using cached ranks (no ballots here).
    for (int i = 0; i < 16; ++i) {
        u32 d = dg[i];
        u32 before = pk[i] & 0xffu;
        u32 base = vwh[d * 4 + w];
        el[base + before] = v[i];
        if (pk[i] & 0x10000u)
            vwh[d * 4 + w] = (u16)(base + ((pk[i] >> 8) & 0xffu));
    }
    __syncthreads();

    // phase C: linear read-back, run-contiguous global write (+ fused
    // next-pass histogram via global atomics).
    if (!final_pass) {
        u64* dst = out_keys + (size_t)s * Pp;
        u32* hseg = hist_next + (size_t)s * BINS * TILES;
        for (int i = 0; i < 16; ++i) {
            int pos = i * 256 + tid;
            u64 e = el[pos];
            u32 d = (u32)(e >> shift) & (BINS - 1);
            u32 g = (u32)(u16)(pos + dl[d]);
            dst[g] = e;
            u32 dn = (u32)(e >> shift_next) & (BINS - 1);
            atomicAdd(&hseg[dn * TILES + (g >> 12)], 1u);   // dest tile = g/4096
        }
    } else {
        const float2* cseg = coords + (size_t)s * Pp;
        float2* oseg = out + (size_t)s * Pp;
        for (int i = 0; i < 16; ++i) {
            int pos = i * 256 + tid;
            u64 e = el[pos];
            u32 d = (u32)(e >> shift) & (BINS - 1);
            u32 g = (u32)(u16)(pos + dl[d]);
            if (g < Kk) {
                u32 idx = (u32)e & 0xffffu;
                oseg[g] = cseg[idx];
            }
        }
    }
}

// ---------------------------------------------------------------------------
// Kernel 4: copy extra_random into rows [K, P) of each segment.
// ---------------------------------------------------------------------------
__global__ __launch_bounds__(256) void extra_copy_kernel(const float2* __restrict__ extra,
                                                         float2* __restrict__ out) {
    int gid = blockIdx.x * blockDim.x + threadIdx.x;   // [0, B*NR)
    int b = gid / NR;
    int j = gid - b * NR;
    out[(size_t)b * Pp + Kk + j] = extra[gid];
}

extern "C" void kernel_launch(void* const* d_in, const int* in_sizes, int n_in,
                              void* d_out, int out_size, void* d_ws, size_t ws_size,
                              hipStream_t stream) {
    const float*  logits = (const float*)d_in[0];   // (B,H,W,C) fp32
    const float2* coords = (const float2*)d_in[1];  // (B,P,2)  fp32
    const float2* extra  = (const float2*)d_in[2];  // (B,NR,2) fp32
    float2* out = (float2*)d_out;

    u64* buf0 = (u64*)d_ws;                          // 25.2 MB
    u64* buf1 = buf0 + (size_t)Bb * Pp;              // 25.2 MB (ping-pong)
    float* planes = (float*)buf1;                    // 4 MB; dead before pass-0 scatter writes buf1

    // hist choreography (all regions dead w.r.t. their aliases when used):
    //  histA: pass-0 counts/offsets, d_out + 0        (sample -> scan -> scatter0 reads)
    //  histB: pass-1 counts/offsets, d_out + 6.29 MB  (scatter0 atomics -> scan -> scatter1 reads)
    //  histC: pass-2 counts,         d_out + 12.6 MB  (scatter1 atomics -> scan reads)
    //  offC : pass-2 offsets, buf1 head (buf1 dead after pass 1) — final scatter
    //         overwrites ALL of d_out, so its offsets must live outside d_out.
    u32* histA = (u32*)d_out;
    u32* histB = histA + HWORDS;
    u32* histC = histB + HWORDS;
    u32* offC  = (u32*)buf1;

    hipMemsetAsync(histB, 0, 2 * HWORDS * sizeof(u32), stream);  // zero histB+histC

    extract_kernel<<<(Bb * Hh * Ww) / 256, 256, 0, stream>>>(logits, planes);
    sample_key_kernel<<<NBLK, 256, 0, stream>>>(planes, coords, buf0, histA);

    // pass 0: bits [16,27)  buf0 -> buf1   (+build histB)
    scan_kernel<<<Bb, 1024, 0, stream>>>(histA, histA);
    scatter_kernel<<<NBLK, 256, 0, stream>>>(buf0, buf1, histA, histB, 16, 27, 0, nullptr, nullptr);
    // pass 1: bits [27,38)  buf1 -> buf0   (+build histC)
    scan_kernel<<<Bb, 1024, 0, stream>>>(histB, histB);
    scatter_kernel<<<NBLK, 256, 0, stream>>>(buf1, buf0, histB, histC, 27, 38, 0, nullptr, nullptr);
    // pass 2: bits [38,47)  buf0 -> out (fused gather+emit)
    scan_kernel<<<Bb, 1024, 0, stream>>>(histC, offC);
    scatter_kernel<<<NBLK, 256, 0, stream>>>(buf0, nullptr, offC, nullptr, 38, 0, 1, coords, out);

    extra_copy_kernel<<<(Bb * NR) / 256, 256, 0, stream>>>(extra, out);
}

// Round 6
// 323.915 us; speedup vs baseline: 1.9751x; 1.9751x over previous
//
#include <hip/hip_runtime.h>
#include <stdint.h>

#define Bb 64
#define Hh 128
#define Ww 128
#define Cc 21
#define Pp 49152          // NUM_SAMPLED
#define Kk 36864          // NUM_UNCERTAIN
#define NR 12288          // NUM_RANDOM

#define BINS 2048         // 11-bit digits; pass shifts 16/27/38 (bits >=47 are 0)
#define TILE 4096         // elements per sort tile
#define TILES 12          // Pp / TILE
#define NBLK (Bb * TILES) // 768 sample/scatter blocks
#define HWORDS ((size_t)Bb * BINS * TILES)   // u32 words per hist table (6.29 MB)

typedef uint32_t u32;
typedef uint64_t u64;
typedef unsigned short u16;

// XCD-affine decode: all TILES blocks of segment s have blk%8 == s%8, so the
// round-robin block->XCD dispatch keeps a segment's r/w window in ONE XCD's
// L2. Performance heuristic only; correctness never depends on placement.
#define DECODE_ST const int s = blk & 63; const int t = blk >> 6;

// 11-bit ballot digit-match: mask of lanes in this wave holding digit d.
__device__ __forceinline__ u64 match11(u32 d) {
    u64 m = ~0ull;
    #pragma unroll
    for (int bit = 0; bit < 11; ++bit) {
        u64 bl = __ballot((d >> bit) & 1u);
        m &= ((d >> bit) & 1u) ? bl : ~bl;
    }
    return m;
}

// ---------------------------------------------------------------------------
// Kernel 0: compact channel-0 plane: planes[b][h][w] = logits[b][h][w][0].
// ---------------------------------------------------------------------------
__global__ __launch_bounds__(256) void extract_kernel(const float* __restrict__ logits,
                                                      float* __restrict__ planes) {
    int gid = blockIdx.x * blockDim.x + threadIdx.x;   // [0, B*H*W)
    planes[gid] = logits[(size_t)gid * Cc];
}

// ---------------------------------------------------------------------------
// Kernel 1: bilinear sample (64 KB plane staged in LDS), build sortable key,
// fused pass-0 per-tile histogram. key = fp32 bits of |interp| (order-
// isomorphic for non-negative floats); element = (key << 16) | idx.
// fp contract OFF: the sort permutation feeds the output directly — bit-exact
// numpy arithmetic required (one rank flip = O(1) absmax error).
// ---------------------------------------------------------------------------
__global__ __launch_bounds__(256) void sample_key_kernel(const float* __restrict__ planes,
                                                         const float2* __restrict__ coords,
                                                         u64* __restrict__ keys,
                                                         u32* __restrict__ hist) {
#pragma clang fp contract(off)
    __shared__ float pl[Hh * Ww];      // 64 KB
    __shared__ u32 h[BINS];            // 8 KB
    const int tid = threadIdx.x;
    const int blk = blockIdx.x;
    DECODE_ST

    for (int i = tid; i < BINS; i += 256) h[i] = 0;
    const float4* p4 = (const float4*)(planes + s * (Hh * Ww));
    float4* l4 = (float4*)pl;
    #pragma unroll
    for (int i = 0; i < 16; ++i) l4[i * 256 + tid] = p4[i * 256 + tid];
    __syncthreads();

    #pragma unroll 4
    for (int i = 0; i < 16; ++i) {
        int idx = t * TILE + i * 256 + tid;            // point index within segment
        int gid = s * Pp + idx;
        float2 c = coords[gid];
        float xf = c.x * 127.0f;                       // coords[...,0] -> H axis
        float yf = c.y * 127.0f;                       // coords[...,1] -> W axis
        float x0 = floorf(xf), x1 = ceilf(xf);
        float y0 = floorf(yf), y1 = ceilf(yf);
        float mux = xf - x0;
        float muy = yf - y0;
        int x0i = (int)x0, x1i = (int)x1, y0i = (int)y0, y1i = (int)y1;
        float p1 = pl[x0i * Ww + y0i];
        float p2 = pl[x1i * Ww + y0i];
        float p3 = pl[x0i * Ww + y1i];
        float p4v = pl[x1i * Ww + y1i];
        float p12 = p1 * (1.0f - mux) + p2 * mux;
        float p34 = p3 * (1.0f - mux) + p4v * mux;
        float r   = p12 * (1.0f - muy) + p34 * muy;
        u32 kb = __float_as_uint(r) & 0x7fffffffu;     // |r| bits
        keys[gid] = ((u64)kb << 16) | (u32)idx;
        atomicAdd(&h[kb & (BINS - 1)], 1u);            // pass-0 digit (uniform)
    }
    __syncthreads();
    for (int j = 0; j < 8; ++j) {
        int d = tid * 8 + j;
        hist[((size_t)s * BINS + d) * TILES + t] = h[d];
    }
}

// ---------------------------------------------------------------------------
// Kernel 2 (passes 1,2): per-tile histogram via per-wave privatized LDS
// counters + plain atomicAdd (no ballots: even the skewed exponent digit has
// only ~3-8-way same-address collisions, far cheaper than 22 VALU ops/elem).
// ---------------------------------------------------------------------------
__global__ __launch_bounds__(256) void hist_kernel(const u64* __restrict__ in,
                                                   u32* __restrict__ hist, int shift) {
    __shared__ u32 h[4][BINS];         // 32 KB, one table per wave
    const int tid = threadIdx.x;
    const int w = tid >> 6;
    const int blk = blockIdx.x;
    DECODE_ST
    for (int i = tid; i < 4 * BINS; i += 256) ((u32*)h)[i] = 0;
    __syncthreads();
    const u64* src = in + (size_t)s * Pp + t * TILE;
    #pragma unroll 4
    for (int i = 0; i < 16; ++i) {
        u64 v = src[i * 256 + tid];
        u32 d = (u32)(v >> shift) & (BINS - 1);
        atomicAdd(&h[w][d], 1u);
    }
    __syncthreads();
    for (int j = 0; j < 8; ++j) {
        int d = tid * 8 + j;
        hist[((size_t)s * BINS + d) * TILES + t] = h[0][d] + h[1][d] + h[2][d] + h[3][d];
    }
}

// ---------------------------------------------------------------------------
// Kernel 3: per-segment exclusive scan: dst[s][d][t] = prefix of src counts
// in (digit, tile) order. src may equal dst (in-place).
// ---------------------------------------------------------------------------
__global__ __launch_bounds__(1024) void scan_kernel(const u32* __restrict__ src,
                                                    u32* __restrict__ dst) {
    __shared__ u32 wsum[16];
    const int s = blockIdx.x;
    const int tid = threadIdx.x;
    const int lane = tid & 63;
    const int w = tid >> 6;
    const u32* sb = src + (size_t)s * BINS * TILES;
    u32* db = dst + (size_t)s * BINS * TILES;
    const int d0 = tid * 2, d1 = tid * 2 + 1;

    u32 c0[TILES], c1[TILES];
    u32 t0 = 0, t1 = 0;
    #pragma unroll
    for (int t = 0; t < TILES; ++t) { c0[t] = sb[d0 * TILES + t]; t0 += c0[t]; }
    #pragma unroll
    for (int t = 0; t < TILES; ++t) { c1[t] = sb[d1 * TILES + t]; t1 += c1[t]; }
    u32 ts = t0 + t1;

    u32 sc = ts;
    for (int o = 1; o < 64; o <<= 1) {
        u32 n = __shfl_up(sc, o);
        if (lane >= o) sc += n;
    }
    if (lane == 63) wsum[w] = sc;
    __syncthreads();
    if (tid == 0) {
        u32 run = 0;
        for (int i = 0; i < 16; ++i) { u32 v = wsum[i]; wsum[i] = run; run += v; }
    }
    __syncthreads();
    u32 excl = sc - ts + wsum[w];

    u32 r = excl;
    #pragma unroll
    for (int t = 0; t < TILES; ++t) { u32 v = c0[t]; db[d0 * TILES + t] = r; r += v; }
    r = excl + t0;
    #pragma unroll
    for (int t = 0; t < TILES; ++t) { u32 v = c1[t]; db[d1 * TILES + t] = r; r += v; }
}

// ---------------------------------------------------------------------------
// Kernel 4: stable scatter with LDS local reorder + linear run-contiguous
// global write. match11 computed ONCE per element (cached digit/rank/count/
// leader flags reused in phase B). NO fused global-atomic histogram (round-5
// lesson: 3.1M scattered global atomics cost ~240 µs, 50x the hist kernel).
// Final pass: emit out[s][g] = coords[s][idx] directly for g < K.
// ---------------------------------------------------------------------------
__global__ __launch_bounds__(256) void scatter_kernel(const u64* __restrict__ in,
                                                      u64* __restrict__ out_keys,
                                                      const u32* __restrict__ off,
                                                      int shift, int final_pass,
                                                      const float2* __restrict__ coords,
                                                      float2* __restrict__ out) {
    __shared__ u64 el[TILE];           // 32 KB
    __shared__ u16 wh[BINS * 4];       // 16 KB  [digit][wave] counts -> local bases
    __shared__ u16 dl[BINS];           // 4 KB   delta[d] (mod 2^16)
    __shared__ u32 aux[4];
    const int tid = threadIdx.x;
    const int lane = tid & 63;
    const int w = tid >> 6;
    const int blk = blockIdx.x;
    DECODE_ST
    const u64* src = in + (size_t)s * Pp + t * TILE;

    for (int i = tid; i < BINS * 4; i += 256) wh[i] = 0;
    u64 v[16];
    #pragma unroll
    for (int i = 0; i < 16; ++i) v[i] = src[w * 1024 + i * 64 + lane];
    __syncthreads();

    // phase A: per-wave digit histogram; cache match results for phase B.
    // pk[i] = before | (cnt << 8) | (leader << 16)
    const u64 ltmask = (1ull << lane) - 1ull;
    u32 dg[16], pk[16];
    volatile u16* vwh = wh;
    #pragma unroll 2
    for (int i = 0; i < 16; ++i) {
        u32 d = (u32)(v[i] >> shift) & (BINS - 1);
        u64 m = match11(d);
        u32 before = (u32)__popcll(m & ltmask);
        u32 cnt = (u32)__popcll(m);
        bool lead = (lane == __ffsll((unsigned long long)m) - 1);
        dg[i] = d;
        pk[i] = before | (cnt << 8) | (lead ? 0x10000u : 0u);
        if (lead) {
            u32 p = d * 4 + w;
            vwh[p] = (u16)(vwh[p] + cnt);
        }
    }
    __syncthreads();

    // scan: thread owns 8 digits; local exclusive digit bases + per-wave bases.
    const int d0 = tid * 8;
    u32 dtot[8];
    u32 t8 = 0;
    #pragma unroll
    for (int j = 0; j < 8; ++j) {
        int d = d0 + j;
        u32 c = (u32)wh[d * 4 + 0] + wh[d * 4 + 1] + wh[d * 4 + 2] + wh[d * 4 + 3];
        dtot[j] = c;
        t8 += c;
    }
    u32 sc = t8;
    for (int o = 1; o < 64; o <<= 1) {
        u32 n = __shfl_up(sc, o);
        if (lane >= o) sc += n;
    }
    if (lane == 63) aux[w] = sc;
    __syncthreads();
    if (tid == 0) {
        u32 run = 0;
        for (int i = 0; i < 4; ++i) { u32 x = aux[i]; aux[i] = run; run += x; }
    }
    __syncthreads();
    u32 run = sc - t8 + aux[w];       // exclusive base for this thread's digits
    #pragma unroll
    for (int j = 0; j < 8; ++j) {
        int d = d0 + j;
        u32 ls = run;                 // local_start[d]
        u32 g = off[((size_t)s * BINS + d) * TILES + t];
        dl[d] = (u16)(g - ls);
        u32 c0 = wh[d * 4 + 0], c1 = wh[d * 4 + 1], c2 = wh[d * 4 + 2];
        wh[d * 4 + 0] = (u16)ls;
        wh[d * 4 + 1] = (u16)(ls + c0);
        wh[d * 4 + 2] = (u16)(ls + c0 + c1);
        wh[d * 4 + 3] = (u16)(ls + c0 + c1 + c2);
        run += dtot[j];
    }
    __syncthreads();

    // phase B: stable scatter into LDS using cached ranks (no ballots here).
    for (int i = 0; i < 16; ++i) {
        u32 d = dg[i];
        u32 before = pk[i] & 0xffu;
        u32 base = vwh[d * 4 + w];
        el[base + before] = v[i];
        if (pk[i] & 0x10000u)
            vwh[d * 4 + w] = (u16)(base + ((pk[i] >> 8) & 0xffu));
    }
    __syncthreads();

    // phase C: linear read-back, run-contiguous global write
    if (!final_pass) {
        u64* dst = out_keys + (size_t)s * Pp;
        for (int i = 0; i < 16; ++i) {
            int pos = i * 256 + tid;
            u64 e = el[pos];
            u32 d = (u32)(e >> shift) & (BINS - 1);
            u32 g = (u32)(u16)(pos + dl[d]);
            dst[g] = e;
        }
    } else {
        const float2* cseg = coords + (size_t)s * Pp;
        float2* oseg = out + (size_t)s * Pp;
        for (int i = 0; i < 16; ++i) {
            int pos = i * 256 + tid;
            u64 e = el[pos];
            u32 d = (u32)(e >> shift) & (BINS - 1);
            u32 g = (u32)(u16)(pos + dl[d]);
            if (g < Kk) {
                u32 idx = (u32)e & 0xffffu;
                oseg[g] = cseg[idx];
            }
        }
    }
}

// ---------------------------------------------------------------------------
// Kernel 5: copy extra_random into rows [K, P) of each segment.
// ---------------------------------------------------------------------------
__global__ __launch_bounds__(256) void extra_copy_kernel(const float2* __restrict__ extra,
                                                         float2* __restrict__ out) {
    int gid = blockIdx.x * blockDim.x + threadIdx.x;   // [0, B*NR)
    int b = gid / NR;
    int j = gid - b * NR;
    out[(size_t)b * Pp + Kk + j] = extra[gid];
}

extern "C" void kernel_launch(void* const* d_in, const int* in_sizes, int n_in,
                              void* d_out, int out_size, void* d_ws, size_t ws_size,
                              hipStream_t stream) {
    const float*  logits = (const float*)d_in[0];   // (B,H,W,C) fp32
    const float2* coords = (const float2*)d_in[1];  // (B,P,2)  fp32
    const float2* extra  = (const float2*)d_in[2];  // (B,NR,2) fp32
    float2* out = (float2*)d_out;

    u64* buf0 = (u64*)d_ws;                          // 25.2 MB
    u64* buf1 = buf0 + (size_t)Bb * Pp;              // 25.2 MB (ping-pong)
    float* planes = (float*)buf1;                    // 4 MB; dead before pass-0 scatter writes buf1
    u32* histA = (u32*)d_out;                        // 6.3 MB scratch (passes 0,1); d_out untouched until final pass
    u32* offC  = (u32*)buf1;                         // pass-2 offsets in buf1 (dead then; final scatter overwrites d_out)

    extract_kernel<<<(Bb * Hh * Ww) / 256, 256, 0, stream>>>(logits, planes);
    sample_key_kernel<<<NBLK, 256, 0, stream>>>(planes, coords, buf0, histA);

    // pass 0: bits [16,27)  buf0 -> buf1
    scan_kernel<<<Bb, 1024, 0, stream>>>(histA, histA);
    scatter_kernel<<<NBLK, 256, 0, stream>>>(buf0, buf1, histA, 16, 0, nullptr, nullptr);
    // pass 1: bits [27,38)  buf1 -> buf0
    hist_kernel<<<NBLK, 256, 0, stream>>>(buf1, histA, 27);
    scan_kernel<<<Bb, 1024, 0, stream>>>(histA, histA);
    scatter_kernel<<<NBLK, 256, 0, stream>>>(buf1, buf0, histA, 27, 0, nullptr, nullptr);
    // pass 2: bits [38,47)  buf0 -> out (fused gather+emit)
    hist_kernel<<<NBLK, 256, 0, stream>>>(buf0, (u32*)buf1, 38);
    scan_kernel<<<Bb, 1024, 0, stream>>>((u32*)buf1, offC);
    scatter_kernel<<<NBLK, 256, 0, stream>>>(buf0, nullptr, offC, 38, 1, coords, out);

    extra_copy_kernel<<<(Bb * NR) / 256, 256, 0, stream>>>(extra, out);
}